// Round 4
// baseline (4823.431 us; speedup 1.0000x reference)
//
#include <hip/hip_runtime.h>

typedef _Float16 f16;
typedef _Float16 f16x2 __attribute__((ext_vector_type(2)));
typedef _Float16 f16x8 __attribute__((ext_vector_type(8)));
typedef float f32x4 __attribute__((ext_vector_type(4)));

#define B_ 64
#define S_ 1024
#define E_ 256
#define H_ 512
#define NG 1536
#define V_ 50257
#define XLS_LD 264      // x LDS row stride (bank-safe)
#define HS_LD 520       // h LDS row stride (bank-safe)

__device__ __forceinline__ float sigm(float x) { return 1.f / (1.f + __expf(-x)); }

#define ALOAD(p) __hip_atomic_load((p), __ATOMIC_RELAXED, __HIP_MEMORY_SCOPE_AGENT)
#define ASTORE(p, v) __hip_atomic_store((p), (v), __ATOMIC_RELAXED, __HIP_MEMORY_SCOPE_AGENT)

// ------------- pack [gate_w slice ; gi_or_gh_w] into fp16 [1536][KK] -------------
__global__ __launch_bounds__(256) void k_packW(const float* __restrict__ gw, int ld, int off,
        const float* __restrict__ g2, f16* __restrict__ W, int KK) {
    int idx = blockIdx.x * 256 + threadIdx.x;
    int per = KK >> 2;
    if (idx >= NG * per) return;
    int row = idx / per;
    int c4 = (idx % per) << 2;
    const float* src = (row < 1024) ? gw + (size_t)row * ld + off + c4
                                    : g2 + (size_t)(row - 1024) * KK + c4;
    float4 v = *reinterpret_cast<const float4*>(src);
    union { f16 h[4]; unsigned long long u; } w;
    w.h[0] = (f16)v.x; w.h[1] = (f16)v.y; w.h[2] = (f16)v.z; w.h[3] = (f16)v.w;
    *reinterpret_cast<unsigned long long*>(W + (size_t)row * KK + c4) = w.u;
}

// ------------------------- emb fp32 -> fp16 (one-time) -------------------------
__global__ __launch_bounds__(256) void k_embconv(const float* __restrict__ emb,
        f16* __restrict__ out) {
    long long i = (long long)blockIdx.x * 256 + threadIdx.x;      // float4 quads
    if (i >= (long long)V_ * E_ / 4) return;
    float4 v = reinterpret_cast<const float4*>(emb)[i];
    union { f16 h[4]; unsigned long long u; } w;
    w.h[0] = (f16)v.x; w.h[1] = (f16)v.y; w.h[2] = (f16)v.z; w.h[3] = (f16)v.w;
    reinterpret_cast<unsigned long long*>(out)[i] = w.u;
}

// ------------------------ fused persistent 2-layer GRU ------------------------
// 256 WGs x 256 thr. group = blk&7 (XCD-local): l = grp>>2 (layer), c = grp&3
// (cluster of 16 batches). gg = blk>>3 in 0..31: WG owns outputs [gg*16, gg*16+16).
// Per output, MFMA A-rows are {r, z, n_h, n_x}: the h-matmul (rows r,z,n_h) and
// x-matmul (rows r,z,n_x) accumulate into ONE C tile -> no pad waste, no Z GEMM.
// Weights live in VGPRs the whole kernel. L1 trails L0 by one step (h0: 4 slots).
// Flags[grp][gg] = completed steps (per-WG atomic store, no RMW). h exchange via
// relaxed agent atomics; ordering from vmcnt(0) drains (proven r2/r3 protocol).
__global__ __launch_bounds__(256, 1) void k_fused(
    const f16* __restrict__ Wx0p, const f16* __restrict__ Wh0p,
    const f16* __restrict__ Wx1p, const f16* __restrict__ Wh1p,
    const float* __restrict__ gb0, const float* __restrict__ gib0, const float* __restrict__ ghb0,
    const float* __restrict__ gb1, const float* __restrict__ gib1, const float* __restrict__ ghb1,
    const int* __restrict__ tok, const f16* __restrict__ embh,
    f16* h0buf, f16* h1buf, int* flags)
{
    __shared__ __align__(16) f16 xls[2][16][XLS_LD];   // L0: prefetched x(t)
    __shared__ __align__(16) f16 HSa[16][HS_LD];       // staged h (h0 for L0 / h1 for L1)
    __shared__ __align__(16) f16 HSb[16][HS_LD];       // L1: staged h0 (x-input)
    __shared__ __align__(16) f16 hx[16][16];           // gathered h_next
    const int blk = blockIdx.x;
    const int grp = blk & 7;
    const int l = grp >> 2, c = grp & 3;
    const int gg = blk >> 3;
    const int i0 = gg << 4;
    const int tid = threadIdx.x;
    const int w = tid >> 6, lane = tid & 63;
    const int bq = lane & 15, j4 = lane >> 4;
    const int aslot = lane & 3, aout = (lane & 15) >> 2;
    const int outA = i0 + (w << 2) + aout;    // A-fragment row's output
    const int oG = i0 + (w << 2) + j4;        // this lane's gate-math output
    int* myf = flags + (grp << 5);
    int* ptf = flags + (((grp + 4) & 7) << 5);

    const float* gb  = l ? gb1 : gb0;
    const float* gib = l ? gib1 : gib0;
    const float* ghb = l ? ghb1 : ghb0;
    const f16* Whp = l ? Wh1p : Wh0p;
    const f16* Wxp = l ? Wx1p : Wx0p;
    const int KX = l ? 512 : 256;

    // ---- A-fragments into VGPRs (constant for all 1024 steps) ----
    // Wh rows: slot 0->r(row out), 1->z(512+out), 2->n_h(1024+out), 3->zero
    // Wx rows: slot 0->r, 1->z, 2->zero, 3->n_x(1024+out)
    f16x8 wh[16], wx[16];
    {
        const int rowH = (aslot < 3) ? (aslot * 512 + outA) : -1;
        const int rowX = (aslot < 2) ? (aslot * 512 + outA) : (aslot == 3 ? 1024 + outA : -1);
        #pragma unroll
        for (int t = 0; t < 16; ++t) {
            f16x8 v{};
            if (rowH >= 0)
                v = *reinterpret_cast<const f16x8*>(Whp + (size_t)rowH * 512 + (t << 5) + (j4 << 3));
            wh[t] = v;
        }
        #pragma unroll
        for (int t = 0; t < 16; ++t) {
            f16x8 v{};
            if (rowX >= 0 && t < (KX >> 5))
                v = *reinterpret_cast<const f16x8*>(Wxp + (size_t)rowX * KX + (t << 5) + (j4 << 3));
            wx[t] = v;
        }
    }
    const float bR = gb[oG], bZ = gb[512 + oG], bI = gib[oG], bH = ghb[oG];

    unsigned long long* h0q = reinterpret_cast<unsigned long long*>(h0buf); // [4][64][128]
    unsigned long long* h1q = reinterpret_cast<unsigned long long*>(h1buf); // [2][64][128]
    const int sb = tid >> 4, sseg = tid & 15;       // x/emb staging decode

    if (l == 0) {
        // prologue: stage x(0)
        {
            int tk = tok[((c << 4) + sb) * S_];
            *reinterpret_cast<f16x8*>(&xls[0][sb][sseg << 4]) =
                *reinterpret_cast<const f16x8*>(embh + (size_t)tk * E_ + (sseg << 4));
            *reinterpret_cast<f16x8*>(&xls[0][sb][(sseg << 4) + 8]) =
                *reinterpret_cast<const f16x8*>(embh + (size_t)tk * E_ + (sseg << 4) + 8);
        }
        __syncthreads();
        for (int s = 0; s < S_; ++s) {
            const int cur = s & 1;
            // ---- poll: own group >= s ; partner (L1, anti-overwrite) >= s-3 ----
            {
                const int* fp = (lane < 32) ? (myf + lane) : (ptf + (lane - 32));
                const int tgt = (lane < 32) ? s : (s > 3 ? s - 3 : 0);
                while (!__all(ALOAD(fp) >= tgt)) {}
            }
            // ---- prefetch x(s+1) into regs (overlaps staging + MFMA) ----
            f16x8 e0{}, e1{};
            const int havex = (s + 1 < S_);
            if (havex) {
                int tk = tok[((c << 4) + sb) * S_ + s + 1];
                e0 = *reinterpret_cast<const f16x8*>(embh + (size_t)tk * E_ + (sseg << 4));
                e1 = *reinterpret_cast<const f16x8*>(embh + (size_t)tk * E_ + (sseg << 4) + 8);
            }
            // ---- stage h0(s) -> LDS (cache-bypassing loads) ----
            {
                const size_t srcb = ((size_t)(s & 3) * 64 + (c << 4)) * 128;
                #pragma unroll
                for (int it = 0; it < 8; ++it) {
                    int j = tid + (it << 8);
                    int b = j >> 7, kq = j & 127;
                    unsigned long long v = ALOAD(h0q + srcb + (b << 7) + kq);
                    *reinterpret_cast<unsigned long long*>(&HSa[b][kq << 2]) = v;
                }
            }
            __syncthreads();
            // ---- MFMA: Wh0 @ h0(s) (K=512) + Wx0 @ x(s) (K=256), one acc tile ----
            f32x4 a0{}, a1{};
            #pragma unroll
            for (int t = 0; t < 16; ++t) {
                f16x8 bf = *reinterpret_cast<const f16x8*>(&HSa[bq][(t << 5) + (j4 << 3)]);
                if (t & 1) a1 = __builtin_amdgcn_mfma_f32_16x16x32_f16(wh[t], bf, a1, 0, 0, 0);
                else       a0 = __builtin_amdgcn_mfma_f32_16x16x32_f16(wh[t], bf, a0, 0, 0, 0);
            }
            #pragma unroll
            for (int t = 0; t < 8; ++t) {
                f16x8 bf = *reinterpret_cast<const f16x8*>(&xls[cur][bq][(t << 5) + (j4 << 3)]);
                if (t & 1) a1 = __builtin_amdgcn_mfma_f32_16x16x32_f16(wx[t], bf, a1, 0, 0, 0);
                else       a0 = __builtin_amdgcn_mfma_f32_16x16x32_f16(wx[t], bf, a0, 0, 0, 0);
            }
            f32x4 d = a0 + a1;                        // rows {r, z, n_h, n_x}
            float r = sigm(d[0] + bR);
            float z = sigm(d[1] + bZ);
            float n = tanhf(d[3] + bI + r * (d[2] + bH));
            float hold = (float)HSa[bq][oG];
            hx[bq][(w << 2) + j4] = (f16)((1.f - z) * n + z * hold);
            if (havex) {
                *reinterpret_cast<f16x8*>(&xls[cur ^ 1][sb][sseg << 4]) = e0;
                *reinterpret_cast<f16x8*>(&xls[cur ^ 1][sb][(sseg << 4) + 8]) = e1;
            }
            __syncthreads();
            // ---- publish h0(s+1) + flag ----
            if (tid < 64) {
                int b = tid >> 2, qq = tid & 3;
                unsigned long long v = *reinterpret_cast<unsigned long long*>(&hx[b][qq << 2]);
                ASTORE(h0q + ((size_t)((s + 1) & 3) * 64 + (c << 4) + b) * 128 + (i0 >> 2) + qq, v);
            }
            asm volatile("s_waitcnt vmcnt(0)" ::: "memory");
            if (tid == 0) ASTORE(myf + gg, s + 1);
        }
    } else {
        for (int s = 0; s < S_; ++s) {
            // ---- poll: own >= s (h1(s)) ; partner L0 >= s+1 (h0(s+1) ready) ----
            {
                const int* fp = (lane < 32) ? (myf + lane) : (ptf + (lane - 32));
                const int tgt = (lane < 32) ? s : s + 1;
                while (!__all(ALOAD(fp) >= tgt)) {}
            }
            // ---- stage h1(s) -> HSa and h0(s+1) -> HSb ----
            {
                const size_t s1 = ((size_t)(s & 1) * 64 + (c << 4)) * 128;
                const size_t s0 = ((size_t)((s + 1) & 3) * 64 + (c << 4)) * 128;
                #pragma unroll
                for (int it = 0; it < 8; ++it) {
                    int j = tid + (it << 8);
                    int b = j >> 7, kq = j & 127;
                    unsigned long long v1 = ALOAD(h1q + s1 + (b << 7) + kq);
                    unsigned long long v0 = ALOAD(h0q + s0 + (b << 7) + kq);
                    *reinterpret_cast<unsigned long long*>(&HSa[b][kq << 2]) = v1;
                    *reinterpret_cast<unsigned long long*>(&HSb[b][kq << 2]) = v0;
                }
            }
            __syncthreads();
            // ---- MFMA: Wh1 @ h1(s) + Wx1 @ h0(s+1), both K=512, one acc tile ----
            f32x4 a0{}, a1{};
            #pragma unroll
            for (int t = 0; t < 16; ++t) {
                f16x8 bf = *reinterpret_cast<const f16x8*>(&HSa[bq][(t << 5) + (j4 << 3)]);
                if (t & 1) a1 = __builtin_amdgcn_mfma_f32_16x16x32_f16(wh[t], bf, a1, 0, 0, 0);
                else       a0 = __builtin_amdgcn_mfma_f32_16x16x32_f16(wh[t], bf, a0, 0, 0, 0);
            }
            #pragma unroll
            for (int t = 0; t < 16; ++t) {
                f16x8 bf = *reinterpret_cast<const f16x8*>(&HSb[bq][(t << 5) + (j4 << 3)]);
                if (t & 1) a1 = __builtin_amdgcn_mfma_f32_16x16x32_f16(wx[t], bf, a1, 0, 0, 0);
                else       a0 = __builtin_amdgcn_mfma_f32_16x16x32_f16(wx[t], bf, a0, 0, 0, 0);
            }
            f32x4 d = a0 + a1;                        // rows {r, z, n_h, n_x}
            float r = sigm(d[0] + bR);
            float z = sigm(d[1] + bZ);
            float n = tanhf(d[3] + bI + r * (d[2] + bH));
            float hold = (float)HSa[bq][oG];
            hx[bq][(w << 2) + j4] = (f16)((1.f - z) * n + z * hold);
            __syncthreads();
            // ---- publish h1(s+1) + flag ----
            if (tid < 64) {
                int b = tid >> 2, qq = tid & 3;
                unsigned long long v = *reinterpret_cast<unsigned long long*>(&hx[b][qq << 2]);
                ASTORE(h1q + ((size_t)((s + 1) & 1) * 64 + (c << 4) + b) * 128 + (i0 >> 2) + qq, v);
            }
            asm volatile("s_waitcnt vmcnt(0)" ::: "memory");
            if (tid == 0) ASTORE(myf + gg, s + 1);
        }
    }
}

// ------------------------------- final head -------------------------------
__global__ __launch_bounds__(64) void k_final(const f16* __restrict__ h,
        const float* __restrict__ fcw, const float* __restrict__ fcb,
        float* __restrict__ out) {
    int b = threadIdx.x;
    float acc = fcb[0];
    for (int k = 0; k < H_; ++k) acc += (float)h[(size_t)b * H_ + k] * fcw[k];
    out[b] = sigm(acc);
}

extern "C" void kernel_launch(void* const* d_in, const int* in_sizes, int n_in,
                              void* d_out, int out_size, void* d_ws, size_t ws_size,
                              hipStream_t stream) {
    (void)in_sizes; (void)n_in; (void)out_size; (void)ws_size;
    const int*   tokens = (const int*)d_in[0];
    const float* emb  = (const float*)d_in[1];
    const float* fc_w = (const float*)d_in[2];
    const float* fc_b = (const float*)d_in[3];
    const float* gw0  = (const float*)d_in[4];
    const float* gb0  = (const float*)d_in[5];
    const float* giw0 = (const float*)d_in[6];
    const float* gib0 = (const float*)d_in[7];
    const float* ghw0 = (const float*)d_in[8];
    const float* ghb0 = (const float*)d_in[9];
    const float* gw1  = (const float*)d_in[10];
    const float* gb1  = (const float*)d_in[11];
    const float* giw1 = (const float*)d_in[12];
    const float* gib1 = (const float*)d_in[13];
    const float* ghw1 = (const float*)d_in[14];
    const float* ghb1 = (const float*)d_in[15];

    char* base = (char*)d_ws;
    size_t off = 0;
    auto carve = [&](size_t bytes) {
        char* p = base + off;
        off = (off + bytes + 255) & ~(size_t)255;
        return p;
    };
    f16*   embh  = (f16*)carve((size_t)V_ * E_ * 2);          // ~25.7 MB
    f16*   Wx0   = (f16*)carve((size_t)NG * 256 * 2);
    f16*   Wh0   = (f16*)carve((size_t)NG * 512 * 2);
    f16*   Wx1   = (f16*)carve((size_t)NG * 512 * 2);
    f16*   Wh1   = (f16*)carve((size_t)NG * 512 * 2);
    f16*   hbuf0 = (f16*)carve((size_t)4 * B_ * H_ * 2);      // 4 slots
    f16*   hbuf1 = (f16*)carve((size_t)2 * B_ * H_ * 2);      // 2 slots
    int*   flags = (int*)carve((size_t)8 * 32 * 4);

    hipMemsetAsync(hbuf0, 0, (size_t)4 * B_ * H_ * 2, stream);
    hipMemsetAsync(hbuf1, 0, (size_t)2 * B_ * H_ * 2, stream);
    hipMemsetAsync(flags, 0, (size_t)8 * 32 * 4, stream);

    k_embconv<<<(V_ * E_ / 4 + 255) / 256, 256, 0, stream>>>(emb, embh);
    k_packW<<<384, 256, 0, stream>>>(gw0, 768, 0,    giw0, Wx0, 256);
    k_packW<<<768, 256, 0, stream>>>(gw0, 768, 256,  ghw0, Wh0, 512);
    k_packW<<<768, 256, 0, stream>>>(gw1, 1024, 0,   giw1, Wx1, 512);
    k_packW<<<768, 256, 0, stream>>>(gw1, 1024, 512, ghw1, Wh1, 512);

    k_fused<<<256, 256, 0, stream>>>(Wx0, Wh0, Wx1, Wh1,
                                     gb0, gib0, ghb0, gb1, gib1, ghb1,
                                     tokens, embh, hbuf0, hbuf1, flags);
    k_final<<<1, 64, 0, stream>>>(hbuf1, fc_w, fc_b, (float*)d_out);
}

// Round 5
// 4644.950 us; speedup vs baseline: 1.0384x; 1.0384x over previous
//
#include <hip/hip_runtime.h>

typedef _Float16 f16;
typedef _Float16 f16x2 __attribute__((ext_vector_type(2)));
typedef _Float16 f16x8 __attribute__((ext_vector_type(8)));
typedef float f32x4 __attribute__((ext_vector_type(4)));

#define B_ 64
#define S_ 1024
#define E_ 256
#define H_ 512
#define NG 1536
#define V_ 50257
#define XLS_LD 280      // x LDS row stride: 560B -> bank-quad step 3 (coprime 8)
#define HS_LD 536       // h LDS row stride: 1072B -> bank-quad step 3 (coprime 8)
#define NSLOT0 8        // h0 pipeline depth (L0 may run up to 7 steps ahead of L1)

__device__ __forceinline__ float sigm(float x) { return 1.f / (1.f + __expf(-x)); }

#define ALOAD(p) __hip_atomic_load((p), __ATOMIC_RELAXED, __HIP_MEMORY_SCOPE_AGENT)
#define ASTORE(p, v) __hip_atomic_store((p), (v), __ATOMIC_RELAXED, __HIP_MEMORY_SCOPE_AGENT)

// ------------- pack [gate_w slice ; gi_or_gh_w] into fp16 [1536][KK] -------------
__global__ __launch_bounds__(256) void k_packW(const float* __restrict__ gw, int ld, int off,
        const float* __restrict__ g2, f16* __restrict__ W, int KK) {
    int idx = blockIdx.x * 256 + threadIdx.x;
    int per = KK >> 2;
    if (idx >= NG * per) return;
    int row = idx / per;
    int c4 = (idx % per) << 2;
    const float* src = (row < 1024) ? gw + (size_t)row * ld + off + c4
                                    : g2 + (size_t)(row - 1024) * KK + c4;
    float4 v = *reinterpret_cast<const float4*>(src);
    union { f16 h[4]; unsigned long long u; } w;
    w.h[0] = (f16)v.x; w.h[1] = (f16)v.y; w.h[2] = (f16)v.z; w.h[3] = (f16)v.w;
    *reinterpret_cast<unsigned long long*>(W + (size_t)row * KK + c4) = w.u;
}

// ------------------------- emb fp32 -> fp16 (one-time) -------------------------
__global__ __launch_bounds__(256) void k_embconv(const float* __restrict__ emb,
        f16* __restrict__ out) {
    long long i = (long long)blockIdx.x * 256 + threadIdx.x;      // float4 quads
    if (i >= (long long)V_ * E_ / 4) return;
    float4 v = reinterpret_cast<const float4*>(emb)[i];
    union { f16 h[4]; unsigned long long u; } w;
    w.h[0] = (f16)v.x; w.h[1] = (f16)v.y; w.h[2] = (f16)v.z; w.h[3] = (f16)v.w;
    reinterpret_cast<unsigned long long*>(out)[i] = w.u;
}

// ------------------------ fused persistent 2-layer GRU ------------------------
// 256 WGs x 256 thr (1/CU). group = blk&7: l = grp>>2 (layer), c = grp&3 (cluster
// of 16 batches). gg = blk>>3 (0..31): WG owns outputs [gg*16, gg*16+16).
// MFMA A-rows per output = {r, z, n_h, n_x}: h-matmul and x-matmul accumulate into
// ONE C tile. Weights pinned in VGPRs via asm (anti-rematerialization). L1 trails
// L0 by up to NSLOT0-1 steps (decoupled). Flags[grp][gg] = completed steps
// (per-WG atomic store). h exchange via relaxed agent atomics; ordering from
// explicit vmcnt(0) drains before flag stores.
__global__ __launch_bounds__(256, 1) void k_fused(
    const f16* __restrict__ Wx0p, const f16* __restrict__ Wh0p,
    const f16* __restrict__ Wx1p, const f16* __restrict__ Wh1p,
    const float* __restrict__ gb0, const float* __restrict__ gib0, const float* __restrict__ ghb0,
    const float* __restrict__ gb1, const float* __restrict__ gib1, const float* __restrict__ ghb1,
    const int* __restrict__ tok, const f16* __restrict__ embh,
    f16* h0buf, f16* h1buf, int* flags)
{
    __shared__ __align__(16) f16 xls[2][16][XLS_LD];   // L0: prefetched x(t)
    __shared__ __align__(16) f16 HSa[16][HS_LD];       // staged h (h0 for L0 / h1 for L1)
    __shared__ __align__(16) f16 HSb[16][HS_LD];       // L1: staged h0 (x-input)
    __shared__ __align__(16) f16 hx[16][20];           // gathered h_next (padded)
    const int blk = blockIdx.x;
    const int grp = blk & 7;
    const int l = grp >> 2, c = grp & 3;
    const int gg = blk >> 3;
    const int i0 = gg << 4;
    const int tid = threadIdx.x;
    const int w = tid >> 6, lane = tid & 63;
    const int bq = lane & 15, j4 = lane >> 4;
    const int aslot = lane & 3, aout = (lane & 15) >> 2;
    const int outA = i0 + (w << 2) + aout;    // A-fragment row's output
    const int oG = i0 + (w << 2) + j4;        // this lane's gate-math output
    int* myf = flags + (grp << 5);
    int* ptf = flags + (((grp + 4) & 7) << 5);

    const float* gb  = l ? gb1 : gb0;
    const float* gib = l ? gib1 : gib0;
    const float* ghb = l ? ghb1 : ghb0;
    const f16* Whp = l ? Wh1p : Wh0p;
    const f16* Wxp = l ? Wx1p : Wx0p;
    const int KX = l ? 512 : 256;
    const int ntx = KX >> 5;

    // ---- A-fragments into VGPRs, pinned (constant for all 1024 steps) ----
    // Wh rows: slot 0->r(out), 1->z(512+out), 2->n_h(1024+out), 3->zero
    // Wx rows: slot 0->r, 1->z, 2->zero, 3->n_x(1024+out)
    f16x8 wh[16], wx[16];
    {
        const int rowH = (aslot < 3) ? (aslot * 512 + outA) : -1;
        const int rowX = (aslot < 2) ? (aslot * 512 + outA) : (aslot == 3 ? 1024 + outA : -1);
        #pragma unroll
        for (int t = 0; t < 16; ++t) {
            f16x8 v{};
            if (rowH >= 0)
                v = *reinterpret_cast<const f16x8*>(Whp + (size_t)rowH * 512 + (t << 5) + (j4 << 3));
            wh[t] = v;
            asm volatile("" : "+v"(wh[t]));           // pin: no rematerialization
        }
        #pragma unroll
        for (int t = 0; t < 16; ++t) {
            f16x8 v{};
            if (rowX >= 0 && t < ntx)
                v = *reinterpret_cast<const f16x8*>(Wxp + (size_t)rowX * KX + (t << 5) + (j4 << 3));
            wx[t] = v;
            if (t < ntx) asm volatile("" : "+v"(wx[t]));   // pin used fragments
        }
    }
    const float bR = gb[oG], bZ = gb[512 + oG], bI = gib[oG], bH = ghb[oG];

    unsigned long long* h0q = reinterpret_cast<unsigned long long*>(h0buf); // [8][64][128]
    unsigned long long* h1q = reinterpret_cast<unsigned long long*>(h1buf); // [2][64][128]
    const int sb = tid >> 4, sseg = tid & 15;       // x/emb staging decode

    if (l == 0) {
        // prologue: stage x(0)
        {
            int tk = tok[((c << 4) + sb) * S_];
            *reinterpret_cast<f16x8*>(&xls[0][sb][sseg << 4]) =
                *reinterpret_cast<const f16x8*>(embh + (size_t)tk * E_ + (sseg << 4));
            *reinterpret_cast<f16x8*>(&xls[0][sb][(sseg << 4) + 8]) =
                *reinterpret_cast<const f16x8*>(embh + (size_t)tk * E_ + (sseg << 4) + 8);
        }
        __syncthreads();
        for (int s = 0; s < S_; ++s) {
            const int cur = s & 1;
            // ---- poll: own group >= s ; partner (L1, anti-overwrite) >= s-7 ----
            {
                const int* fp = (lane < 32) ? (myf + lane) : (ptf + (lane - 32));
                const int tgt = (lane < 32) ? s : (s > 7 ? s - 7 : 0);
                while (!__all(ALOAD(fp) >= tgt)) {}
            }
            // ---- prefetch x(s+1) into regs (overlaps staging + MFMA) ----
            f16x8 e0{}, e1{};
            const int havex = (s + 1 < S_);
            if (havex) {
                int tk = tok[((c << 4) + sb) * S_ + s + 1];
                e0 = *reinterpret_cast<const f16x8*>(embh + (size_t)tk * E_ + (sseg << 4));
                e1 = *reinterpret_cast<const f16x8*>(embh + (size_t)tk * E_ + (sseg << 4) + 8);
            }
            // ---- stage h0(s) -> LDS (cache-bypassing loads) ----
            {
                const size_t srcb = ((size_t)(s & (NSLOT0 - 1)) * 64 + (c << 4)) * 128;
                #pragma unroll
                for (int it = 0; it < 8; ++it) {
                    int j = tid + (it << 8);
                    int b = j >> 7, kq = j & 127;
                    unsigned long long v = ALOAD(h0q + srcb + (b << 7) + kq);
                    *reinterpret_cast<unsigned long long*>(&HSa[b][kq << 2]) = v;
                }
            }
            __syncthreads();
            // ---- MFMA: Wh0 @ h0(s) (K=512) + Wx0 @ x(s) (K=256), one acc tile ----
            f32x4 a0{}, a1{};
            #pragma unroll
            for (int t = 0; t < 16; ++t) {
                f16x8 bf = *reinterpret_cast<const f16x8*>(&HSa[bq][(t << 5) + (j4 << 3)]);
                if (t & 1) a1 = __builtin_amdgcn_mfma_f32_16x16x32_f16(wh[t], bf, a1, 0, 0, 0);
                else       a0 = __builtin_amdgcn_mfma_f32_16x16x32_f16(wh[t], bf, a0, 0, 0, 0);
            }
            #pragma unroll
            for (int t = 0; t < 8; ++t) {
                f16x8 bf = *reinterpret_cast<const f16x8*>(&xls[cur][bq][(t << 5) + (j4 << 3)]);
                if (t & 1) a1 = __builtin_amdgcn_mfma_f32_16x16x32_f16(wx[t], bf, a1, 0, 0, 0);
                else       a0 = __builtin_amdgcn_mfma_f32_16x16x32_f16(wx[t], bf, a0, 0, 0, 0);
            }
            f32x4 d = a0 + a1;                        // rows {r, z, n_h, n_x}
            float r = sigm(d[0] + bR);
            float z = sigm(d[1] + bZ);
            float n = tanhf(d[3] + bI + r * (d[2] + bH));
            float hold = (float)HSa[bq][oG];
            hx[bq][(w << 2) + j4] = (f16)((1.f - z) * n + z * hold);
            if (havex) {
                *reinterpret_cast<f16x8*>(&xls[cur ^ 1][sb][sseg << 4]) = e0;
                *reinterpret_cast<f16x8*>(&xls[cur ^ 1][sb][(sseg << 4) + 8]) = e1;
            }
            __syncthreads();
            // ---- publish h0(s+1) + flag ----
            if (tid < 64) {
                int b = tid >> 2, qq = tid & 3;
                unsigned long long v = *reinterpret_cast<unsigned long long*>(&hx[b][qq << 2]);
                ASTORE(h0q + ((size_t)((s + 1) & (NSLOT0 - 1)) * 64 + (c << 4) + b) * 128 + (i0 >> 2) + qq, v);
            }
            asm volatile("s_waitcnt vmcnt(0)" ::: "memory");
            if (tid == 0) ASTORE(myf + gg, s + 1);
        }
    } else {
        for (int s = 0; s < S_; ++s) {
            // ---- poll: own >= s (h1(s)) ; partner L0 flag >= s+1 (h0(s+1) ready) ----
            {
                const int* fp = (lane < 32) ? (myf + lane) : (ptf + (lane - 32));
                const int tgt = (lane < 32) ? s : s + 1;
                while (!__all(ALOAD(fp) >= tgt)) {}
            }
            // ---- stage h1(s) -> HSa and h0(s+1) -> HSb ----
            {
                const size_t s1 = ((size_t)(s & 1) * 64 + (c << 4)) * 128;
                const size_t s0 = ((size_t)((s + 1) & (NSLOT0 - 1)) * 64 + (c << 4)) * 128;
                #pragma unroll
                for (int it = 0; it < 8; ++it) {
                    int j = tid + (it << 8);
                    int b = j >> 7, kq = j & 127;
                    unsigned long long v1 = ALOAD(h1q + s1 + (b << 7) + kq);
                    unsigned long long v0 = ALOAD(h0q + s0 + (b << 7) + kq);
                    *reinterpret_cast<unsigned long long*>(&HSa[b][kq << 2]) = v1;
                    *reinterpret_cast<unsigned long long*>(&HSb[b][kq << 2]) = v0;
                }
            }
            __syncthreads();
            // ---- MFMA: Wh1 @ h1(s) + Wx1 @ h0(s+1), both K=512, one acc tile ----
            f32x4 a0{}, a1{};
            #pragma unroll
            for (int t = 0; t < 16; ++t) {
                f16x8 bf = *reinterpret_cast<const f16x8*>(&HSa[bq][(t << 5) + (j4 << 3)]);
                if (t & 1) a1 = __builtin_amdgcn_mfma_f32_16x16x32_f16(wh[t], bf, a1, 0, 0, 0);
                else       a0 = __builtin_amdgcn_mfma_f32_16x16x32_f16(wh[t], bf, a0, 0, 0, 0);
            }
            #pragma unroll
            for (int t = 0; t < 16; ++t) {
                f16x8 bf = *reinterpret_cast<const f16x8*>(&HSb[bq][(t << 5) + (j4 << 3)]);
                if (t & 1) a1 = __builtin_amdgcn_mfma_f32_16x16x32_f16(wx[t], bf, a1, 0, 0, 0);
                else       a0 = __builtin_amdgcn_mfma_f32_16x16x32_f16(wx[t], bf, a0, 0, 0, 0);
            }
            f32x4 d = a0 + a1;                        // rows {r, z, n_h, n_x}
            float r = sigm(d[0] + bR);
            float z = sigm(d[1] + bZ);
            float n = tanhf(d[3] + bI + r * (d[2] + bH));
            float hold = (float)HSa[bq][oG];
            hx[bq][(w << 2) + j4] = (f16)((1.f - z) * n + z * hold);
            __syncthreads();
            // ---- publish h1(s+1) + flag ----
            if (tid < 64) {
                int b = tid >> 2, qq = tid & 3;
                unsigned long long v = *reinterpret_cast<unsigned long long*>(&hx[b][qq << 2]);
                ASTORE(h1q + ((size_t)((s + 1) & 1) * 64 + (c << 4) + b) * 128 + (i0 >> 2) + qq, v);
            }
            asm volatile("s_waitcnt vmcnt(0)" ::: "memory");
            if (tid == 0) ASTORE(myf + gg, s + 1);
        }
    }
}

// ------------------------------- final head -------------------------------
__global__ __launch_bounds__(64) void k_final(const f16* __restrict__ h,
        const float* __restrict__ fcw, const float* __restrict__ fcb,
        float* __restrict__ out) {
    int b = threadIdx.x;
    float acc = fcb[0];
    for (int k = 0; k < H_; ++k) acc += (float)h[(size_t)b * H_ + k] * fcw[k];
    out[b] = sigm(acc);
}

extern "C" void kernel_launch(void* const* d_in, const int* in_sizes, int n_in,
                              void* d_out, int out_size, void* d_ws, size_t ws_size,
                              hipStream_t stream) {
    (void)in_sizes; (void)n_in; (void)out_size; (void)ws_size;
    const int*   tokens = (const int*)d_in[0];
    const float* emb  = (const float*)d_in[1];
    const float* fc_w = (const float*)d_in[2];
    const float* fc_b = (const float*)d_in[3];
    const float* gw0  = (const float*)d_in[4];
    const float* gb0  = (const float*)d_in[5];
    const float* giw0 = (const float*)d_in[6];
    const float* gib0 = (const float*)d_in[7];
    const float* ghw0 = (const float*)d_in[8];
    const float* ghb0 = (const float*)d_in[9];
    const float* gw1  = (const float*)d_in[10];
    const float* gb1  = (const float*)d_in[11];
    const float* giw1 = (const float*)d_in[12];
    const float* gib1 = (const float*)d_in[13];
    const float* ghw1 = (const float*)d_in[14];
    const float* ghb1 = (const float*)d_in[15];

    char* base = (char*)d_ws;
    size_t off = 0;
    auto carve = [&](size_t bytes) {
        char* p = base + off;
        off = (off + bytes + 255) & ~(size_t)255;
        return p;
    };
    f16*   embh  = (f16*)carve((size_t)V_ * E_ * 2);          // ~25.7 MB
    f16*   Wx0   = (f16*)carve((size_t)NG * 256 * 2);
    f16*   Wh0   = (f16*)carve((size_t)NG * 512 * 2);
    f16*   Wx1   = (f16*)carve((size_t)NG * 512 * 2);
    f16*   Wh1   = (f16*)carve((size_t)NG * 512 * 2);
    f16*   hbuf0 = (f16*)carve((size_t)NSLOT0 * B_ * H_ * 2); // 8 slots
    f16*   hbuf1 = (f16*)carve((size_t)2 * B_ * H_ * 2);      // 2 slots
    int*   flags = (int*)carve((size_t)8 * 32 * 4);

    hipMemsetAsync(hbuf0, 0, (size_t)NSLOT0 * B_ * H_ * 2, stream);
    hipMemsetAsync(hbuf1, 0, (size_t)2 * B_ * H_ * 2, stream);
    hipMemsetAsync(flags, 0, (size_t)8 * 32 * 4, stream);

    k_embconv<<<(V_ * E_ / 4 + 255) / 256, 256, 0, stream>>>(emb, embh);
    k_packW<<<384, 256, 0, stream>>>(gw0, 768, 0,    giw0, Wx0, 256);
    k_packW<<<768, 256, 0, stream>>>(gw0, 768, 256,  ghw0, Wh0, 512);
    k_packW<<<768, 256, 0, stream>>>(gw1, 1024, 0,   giw1, Wx1, 512);
    k_packW<<<768, 256, 0, stream>>>(gw1, 1024, 512, ghw1, Wh1, 512);

    k_fused<<<256, 256, 0, stream>>>(Wx0, Wh0, Wx1, Wh1,
                                     gb0, gib0, ghb0, gb1, gib1, ghb1,
                                     tokens, embh, hbuf0, hbuf1, flags);
    k_final<<<1, 64, 0, stream>>>(hbuf1, fc_w, fc_b, (float*)d_out);
}

// Round 6
// 4484.071 us; speedup vs baseline: 1.0757x; 1.0359x over previous
//
#include <hip/hip_runtime.h>

typedef _Float16 f16;
typedef _Float16 f16x8 __attribute__((ext_vector_type(8)));
typedef float f32x4 __attribute__((ext_vector_type(4)));

#define B_ 64
#define S_ 1024
#define E_ 256
#define H_ 512
#define NG 1536
#define V_ 50257
#define HS_LD 520       // f16 stride: 260 dw, bank-quad step 65 (odd) -> rows on distinct quads
#define XLS_LD 264      // f16 stride: 132 dw, quad step 33 (odd)
#define NS0 16          // h0 ring depth: L0 runs up to 15 steps ahead of L1
#define NS1 4           // h1 ring depth

__device__ __forceinline__ float sigm(float x) { return 1.f / (1.f + __expf(-x)); }

#define ALOAD(p) __hip_atomic_load((p), __ATOMIC_RELAXED, __HIP_MEMORY_SCOPE_AGENT)
#define ASTORE(p, v) __hip_atomic_store((p), (v), __ATOMIC_RELAXED, __HIP_MEMORY_SCOPE_AGENT)

// ------------- pack [gate_w slice ; gi_or_gh_w] into fp16 [1536][KK] -------------
__global__ __launch_bounds__(256) void k_packW(const float* __restrict__ gw, int ld, int off,
        const float* __restrict__ g2, f16* __restrict__ W, int KK) {
    int idx = blockIdx.x * 256 + threadIdx.x;
    int per = KK >> 2;
    if (idx >= NG * per) return;
    int row = idx / per;
    int c4 = (idx % per) << 2;
    const float* src = (row < 1024) ? gw + (size_t)row * ld + off + c4
                                    : g2 + (size_t)(row - 1024) * KK + c4;
    float4 v = *reinterpret_cast<const float4*>(src);
    union { f16 h[4]; unsigned long long u; } w;
    w.h[0] = (f16)v.x; w.h[1] = (f16)v.y; w.h[2] = (f16)v.z; w.h[3] = (f16)v.w;
    *reinterpret_cast<unsigned long long*>(W + (size_t)row * KK + c4) = w.u;
}

// ------------------------- emb fp32 -> fp16 (one-time) -------------------------
__global__ __launch_bounds__(256) void k_embconv(const float* __restrict__ emb,
        f16* __restrict__ out) {
    long long i = (long long)blockIdx.x * 256 + threadIdx.x;      // float4 quads
    if (i >= (long long)V_ * E_ / 4) return;
    float4 v = reinterpret_cast<const float4*>(emb)[i];
    union { f16 h[4]; unsigned long long u; } w;
    w.h[0] = (f16)v.x; w.h[1] = (f16)v.y; w.h[2] = (f16)v.z; w.h[3] = (f16)v.w;
    reinterpret_cast<unsigned long long*>(out)[i] = w.u;
}

// ------------------------ fused persistent 2-layer GRU ------------------------
// 256 WGs x 256 thr (1/CU). grp = blk&15 (XCD-local since members share blk%8):
// l = grp>>3 (layer), c = grp&7 (cluster of 8 batches). gg = blk>>4 (0..15):
// WG owns 32 outputs [gg*32, gg*32+32); each of 4 waves owns 8 = 2 MFMA tiles.
// A-rows per output = {r, z, n_h, n_x}: h-matmul + x-matmul accumulate into ONE
// C tile. MFMA N=8 real batches (cols 8-15 duplicates). Weights VGPR/AGPR-
// resident for all 1024 steps. L1 trails L0 by up to NS0-1 steps (partner polls
// pass instantly in steady state). Flags[grp][gg] = completed steps (plain
// per-WG atomic store). h exchange via relaxed agent atomics; ordering from
// explicit vmcnt(0) drains before flag stores (proven r2-r5 protocol).
__global__ __launch_bounds__(256, 1) void k_fused(
    const f16* __restrict__ Wx0p, const f16* __restrict__ Wh0p,
    const f16* __restrict__ Wx1p, const f16* __restrict__ Wh1p,
    const float* __restrict__ gb0, const float* __restrict__ gib0, const float* __restrict__ ghb0,
    const float* __restrict__ gb1, const float* __restrict__ gib1, const float* __restrict__ ghb1,
    const int* __restrict__ tok, const f16* __restrict__ embh,
    f16* h0buf, f16* h1buf, int* flags)
{
    __shared__ __align__(16) f16 HSh[8][HS_LD];        // h-state (h0 for L0 / h1 for L1)
    __shared__ __align__(16) f16 HSx[8][HS_LD];        // L1: staged h0 (x-input)
    __shared__ __align__(16) f16 xls[2][8][XLS_LD];    // L0: prefetched x(t)
    __shared__ __align__(16) f16 hx[8][40];            // gathered h_next (bank-spread)
    const int blk = blockIdx.x;
    const int grp = blk & 15;
    const int l = grp >> 3, c = grp & 7;
    const int gg = blk >> 4;                           // 0..15
    const int i0 = gg << 5;
    const int tid = threadIdx.x;
    const int w = tid >> 6, lane = tid & 63;
    const int colb = lane & 15, bq = lane & 7, j4 = lane >> 4;
    const int rrow = lane & 15, aout = rrow >> 2, aslot = rrow & 3;
    const int base = i0 + (w << 3);
    const int oA = base + j4, oB = base + 4 + j4;      // this lane's gate-math outputs
    int* myf = flags + (grp << 4);
    int* ptf = flags + (((grp + 8) & 15) << 4);
    const int fidx = lane & 15;
    const int par = (lane >> 4) & 1;                   // lanes 16-31,48-63 watch partner
    const int* fp = par ? (ptf + fidx) : (myf + fidx);
    unsigned long long* h0q = reinterpret_cast<unsigned long long*>(h0buf); // [NS0][64][128]
    unsigned long long* h1q = reinterpret_cast<unsigned long long*>(h1buf); // [NS1][64][128]

    if (l == 0) {
        // ---- weights into registers (constant all steps) ----
        f16x8 wh[2][16], wx[2][8];
        #pragma unroll
        for (int tl = 0; tl < 2; ++tl) {
            const int out = base + (tl << 2) + aout;
            const int rowH = (aslot < 3) ? (aslot * 512 + out) : -1;
            const int rowX = (aslot < 2) ? (aslot * 512 + out) : (aslot == 3 ? 1024 + out : -1);
            #pragma unroll
            for (int t = 0; t < 16; ++t) {
                f16x8 v{};
                if (rowH >= 0) v = *(const f16x8*)(Wh0p + (size_t)rowH * 512 + (t << 5) + (j4 << 3));
                wh[tl][t] = v;
            }
            #pragma unroll
            for (int t = 0; t < 8; ++t) {
                f16x8 v{};
                if (rowX >= 0) v = *(const f16x8*)(Wx0p + (size_t)rowX * 256 + (t << 5) + (j4 << 3));
                wx[tl][t] = v;
            }
        }
        const float bRA = gb0[oA], bZA = gb0[512 + oA], bIA = gib0[oA], bHA = ghb0[oA];
        const float bRB = gb0[oB], bZB = gb0[512 + oB], bIB = gib0[oB], bHB = ghb0[oB];
        const int sb = (tid >> 4) & 7, sseg = tid & 15;
        // prologue: stage x(0)
        if (tid < 128) {
            int tk = tok[((c << 3) + sb) * S_];
            *(f16x8*)&xls[0][sb][sseg << 4] = *(const f16x8*)(embh + (size_t)tk * E_ + (sseg << 4));
            *(f16x8*)&xls[0][sb][(sseg << 4) + 8] = *(const f16x8*)(embh + (size_t)tk * E_ + (sseg << 4) + 8);
        }
        for (int s = 0; s < S_; ++s) {
            const int cur = s & 1;
            // poll: own group >= s ; partner (L1 anti-overwrite) >= s-15
            const int tgt = par ? (s > (NS0 - 1) ? s - (NS0 - 1) : 0) : s;
            while (!__all(ALOAD(fp) >= tgt)) {}
            // prefetch x(s+1) into regs (overlaps stage + MFMA)
            f16x8 e0{}, e1{};
            const bool havex = (tid < 128) && (s + 1 < S_);
            if (havex) {
                int tk = tok[((c << 3) + sb) * S_ + s + 1];
                e0 = *(const f16x8*)(embh + (size_t)tk * E_ + (sseg << 4));
                e1 = *(const f16x8*)(embh + (size_t)tk * E_ + (sseg << 4) + 8);
            }
            // stage h0(s): 8 rows x 512 = 1024 qwords, 4/thread
            {
                const size_t srcb = ((size_t)(s & (NS0 - 1)) * 64 + (c << 3)) * 128;
                #pragma unroll
                for (int it = 0; it < 4; ++it) {
                    int j = tid + (it << 8);
                    int b = j >> 7, kq = j & 127;
                    unsigned long long v = ALOAD(h0q + srcb + (b << 7) + kq);
                    *(unsigned long long*)&HSh[b][kq << 2] = v;
                }
            }
            __syncthreads();
            // MFMA: Wh0 @ h0(s) (K=512) + Wx0 @ x(s) (K=256), 2 tiles, shared B
            f32x4 p00{}, p01{}, p10{}, p11{};
            #pragma unroll
            for (int t = 0; t < 16; ++t) {
                f16x8 bf = *(const f16x8*)&HSh[bq][(t << 5) + (j4 << 3)];
                if (t & 1) { p01 = __builtin_amdgcn_mfma_f32_16x16x32_f16(wh[0][t], bf, p01, 0, 0, 0);
                             p11 = __builtin_amdgcn_mfma_f32_16x16x32_f16(wh[1][t], bf, p11, 0, 0, 0); }
                else       { p00 = __builtin_amdgcn_mfma_f32_16x16x32_f16(wh[0][t], bf, p00, 0, 0, 0);
                             p10 = __builtin_amdgcn_mfma_f32_16x16x32_f16(wh[1][t], bf, p10, 0, 0, 0); }
            }
            #pragma unroll
            for (int t = 0; t < 8; ++t) {
                f16x8 bf = *(const f16x8*)&xls[cur][bq][(t << 5) + (j4 << 3)];
                if (t & 1) { p01 = __builtin_amdgcn_mfma_f32_16x16x32_f16(wx[0][t], bf, p01, 0, 0, 0);
                             p11 = __builtin_amdgcn_mfma_f32_16x16x32_f16(wx[1][t], bf, p11, 0, 0, 0); }
                else       { p00 = __builtin_amdgcn_mfma_f32_16x16x32_f16(wx[0][t], bf, p00, 0, 0, 0);
                             p10 = __builtin_amdgcn_mfma_f32_16x16x32_f16(wx[1][t], bf, p10, 0, 0, 0); }
            }
            f32x4 dA = p00 + p01, dB = p10 + p11;      // rows {r, z, n_h, n_x}
            if (colb < 8) {
                float rA = sigm(dA[0] + bRA), zA = sigm(dA[1] + bZA);
                float nA = tanhf(dA[3] + bIA + rA * (dA[2] + bHA));
                float hA = (float)HSh[bq][oA];
                float rB = sigm(dB[0] + bRB), zB = sigm(dB[1] + bZB);
                float nB = tanhf(dB[3] + bIB + rB * (dB[2] + bHB));
                float hB = (float)HSh[bq][oB];
                hx[bq][(w << 3) + j4]     = (f16)((1.f - zA) * nA + zA * hA);
                hx[bq][(w << 3) + 4 + j4] = (f16)((1.f - zB) * nB + zB * hB);
            }
            if (havex) {
                *(f16x8*)&xls[cur ^ 1][sb][sseg << 4] = e0;
                *(f16x8*)&xls[cur ^ 1][sb][(sseg << 4) + 8] = e1;
            }
            __syncthreads();
            // publish h0(s+1) + flag
            if (tid < 64) {
                int b = tid >> 3, seg = tid & 7;
                unsigned long long v = *(unsigned long long*)&hx[b][seg << 2];
                ASTORE(h0q + ((size_t)((s + 1) & (NS0 - 1)) * 64 + (c << 3) + b) * 128 + (gg << 3) + seg, v);
            }
            asm volatile("s_waitcnt vmcnt(0)" ::: "memory");
            if (tid == 0) ASTORE(myf + gg, s + 1);
        }
    } else {
        // ---- weights into registers ----
        f16x8 wh[2][16], wx[2][16];
        #pragma unroll
        for (int tl = 0; tl < 2; ++tl) {
            const int out = base + (tl << 2) + aout;
            const int rowH = (aslot < 3) ? (aslot * 512 + out) : -1;
            const int rowX = (aslot < 2) ? (aslot * 512 + out) : (aslot == 3 ? 1024 + out : -1);
            #pragma unroll
            for (int t = 0; t < 16; ++t) {
                f16x8 v{};
                if (rowH >= 0) v = *(const f16x8*)(Wh1p + (size_t)rowH * 512 + (t << 5) + (j4 << 3));
                wh[tl][t] = v;
            }
            #pragma unroll
            for (int t = 0; t < 16; ++t) {
                f16x8 v{};
                if (rowX >= 0) v = *(const f16x8*)(Wx1p + (size_t)rowX * 512 + (t << 5) + (j4 << 3));
                wx[tl][t] = v;
            }
        }
        const float bRA = gb1[oA], bZA = gb1[512 + oA], bIA = gib1[oA], bHA = ghb1[oA];
        const float bRB = gb1[oB], bZB = gb1[512 + oB], bIB = gib1[oB], bHB = ghb1[oB];
        for (int s = 0; s < S_; ++s) {
            // poll: own >= s (h1(s)) ; partner L0 >= s+1 (h0(s+1) ready; ~instant in steady state)
            const int tgt = par ? (s + 1) : s;
            while (!__all(ALOAD(fp) >= tgt)) {}
            // stage h1(s) -> HSh and h0(s+1) -> HSx
            {
                const size_t s1 = ((size_t)(s & (NS1 - 1)) * 64 + (c << 3)) * 128;
                const size_t s0 = ((size_t)((s + 1) & (NS0 - 1)) * 64 + (c << 3)) * 128;
                #pragma unroll
                for (int it = 0; it < 4; ++it) {
                    int j = tid + (it << 8);
                    int b = j >> 7, kq = j & 127;
                    unsigned long long v1 = ALOAD(h1q + s1 + (b << 7) + kq);
                    unsigned long long v0 = ALOAD(h0q + s0 + (b << 7) + kq);
                    *(unsigned long long*)&HSh[b][kq << 2] = v1;
                    *(unsigned long long*)&HSx[b][kq << 2] = v0;
                }
            }
            __syncthreads();
            // MFMA: Wh1 @ h1(s) + Wx1 @ h0(s+1), both K=512, 2 tiles, shared B
            f32x4 p00{}, p01{}, p10{}, p11{};
            #pragma unroll
            for (int t = 0; t < 16; ++t) {
                f16x8 bf = *(const f16x8*)&HSh[bq][(t << 5) + (j4 << 3)];
                if (t & 1) { p01 = __builtin_amdgcn_mfma_f32_16x16x32_f16(wh[0][t], bf, p01, 0, 0, 0);
                             p11 = __builtin_amdgcn_mfma_f32_16x16x32_f16(wh[1][t], bf, p11, 0, 0, 0); }
                else       { p00 = __builtin_amdgcn_mfma_f32_16x16x32_f16(wh[0][t], bf, p00, 0, 0, 0);
                             p10 = __builtin_amdgcn_mfma_f32_16x16x32_f16(wh[1][t], bf, p10, 0, 0, 0); }
            }
            #pragma unroll
            for (int t = 0; t < 16; ++t) {
                f16x8 bf = *(const f16x8*)&HSx[bq][(t << 5) + (j4 << 3)];
                if (t & 1) { p01 = __builtin_amdgcn_mfma_f32_16x16x32_f16(wx[0][t], bf, p01, 0, 0, 0);
                             p11 = __builtin_amdgcn_mfma_f32_16x16x32_f16(wx[1][t], bf, p11, 0, 0, 0); }
                else       { p00 = __builtin_amdgcn_mfma_f32_16x16x32_f16(wx[0][t], bf, p00, 0, 0, 0);
                             p10 = __builtin_amdgcn_mfma_f32_16x16x32_f16(wx[1][t], bf, p10, 0, 0, 0); }
            }
            f32x4 dA = p00 + p01, dB = p10 + p11;      // rows {r, z, n_h, n_x}
            if (colb < 8) {
                float rA = sigm(dA[0] + bRA), zA = sigm(dA[1] + bZA);
                float nA = tanhf(dA[3] + bIA + rA * (dA[2] + bHA));
                float hA = (float)HSh[bq][oA];
                float rB = sigm(dB[0] + bRB), zB = sigm(dB[1] + bZB);
                float nB = tanhf(dB[3] + bIB + rB * (dB[2] + bHB));
                float hB = (float)HSh[bq][oB];
                hx[bq][(w << 3) + j4]     = (f16)((1.f - zA) * nA + zA * hA);
                hx[bq][(w << 3) + 4 + j4] = (f16)((1.f - zB) * nB + zB * hB);
            }
            __syncthreads();
            // publish h1(s+1) + flag
            if (tid < 64) {
                int b = tid >> 3, seg = tid & 7;
                unsigned long long v = *(unsigned long long*)&hx[b][seg << 2];
                ASTORE(h1q + ((size_t)((s + 1) & (NS1 - 1)) * 64 + (c << 3) + b) * 128 + (gg << 3) + seg, v);
            }
            asm volatile("s_waitcnt vmcnt(0)" ::: "memory");
            if (tid == 0) ASTORE(myf + gg, s + 1);
        }
    }
}

// ------------------------------- final head -------------------------------
__global__ __launch_bounds__(64) void k_final(const f16* __restrict__ h,
        const float* __restrict__ fcw, const float* __restrict__ fcb,
        float* __restrict__ out) {
    int b = threadIdx.x;
    float acc = fcb[0];
    for (int k = 0; k < H_; ++k) acc += (float)h[(size_t)b * H_ + k] * fcw[k];
    out[b] = sigm(acc);
}

extern "C" void kernel_launch(void* const* d_in, const int* in_sizes, int n_in,
                              void* d_out, int out_size, void* d_ws, size_t ws_size,
                              hipStream_t stream) {
    (void)in_sizes; (void)n_in; (void)out_size; (void)ws_size;
    const int*   tokens = (const int*)d_in[0];
    const float* emb  = (const float*)d_in[1];
    const float* fc_w = (const float*)d_in[2];
    const float* fc_b = (const float*)d_in[3];
    const float* gw0  = (const float*)d_in[4];
    const float* gb0  = (const float*)d_in[5];
    const float* giw0 = (const float*)d_in[6];
    const float* gib0 = (const float*)d_in[7];
    const float* ghw0 = (const float*)d_in[8];
    const float* ghb0 = (const float*)d_in[9];
    const float* gw1  = (const float*)d_in[10];
    const float* gb1  = (const float*)d_in[11];
    const float* giw1 = (const float*)d_in[12];
    const float* gib1 = (const float*)d_in[13];
    const float* ghw1 = (const float*)d_in[14];
    const float* ghb1 = (const float*)d_in[15];

    char* base = (char*)d_ws;
    size_t off = 0;
    auto carve = [&](size_t bytes) {
        char* p = base + off;
        off = (off + bytes + 255) & ~(size_t)255;
        return p;
    };
    f16*   embh  = (f16*)carve((size_t)V_ * E_ * 2);          // ~25.7 MB
    f16*   Wx0   = (f16*)carve((size_t)NG * 256 * 2);
    f16*   Wh0   = (f16*)carve((size_t)NG * 512 * 2);
    f16*   Wx1   = (f16*)carve((size_t)NG * 512 * 2);
    f16*   Wh1   = (f16*)carve((size_t)NG * 512 * 2);
    f16*   hbuf0 = (f16*)carve((size_t)NS0 * B_ * H_ * 2);    // 1 MB ring
    f16*   hbuf1 = (f16*)carve((size_t)NS1 * B_ * H_ * 2);    // 256 KB ring
    int*   flags = (int*)carve((size_t)16 * 16 * 4);

    hipMemsetAsync(hbuf0, 0, (size_t)NS0 * B_ * H_ * 2, stream);
    hipMemsetAsync(hbuf1, 0, (size_t)NS1 * B_ * H_ * 2, stream);
    hipMemsetAsync(flags, 0, (size_t)16 * 16 * 4, stream);

    k_embconv<<<(V_ * E_ / 4 + 255) / 256, 256, 0, stream>>>(emb, embh);
    k_packW<<<384, 256, 0, stream>>>(gw0, 768, 0,    giw0, Wx0, 256);
    k_packW<<<768, 256, 0, stream>>>(gw0, 768, 256,  ghw0, Wh0, 512);
    k_packW<<<768, 256, 0, stream>>>(gw1, 1024, 0,   giw1, Wx1, 512);
    k_packW<<<768, 256, 0, stream>>>(gw1, 1024, 512, ghw1, Wh1, 512);

    k_fused<<<256, 256, 0, stream>>>(Wx0, Wh0, Wx1, Wh1,
                                     gb0, gib0, ghb0, gb1, gib1, ghb1,
                                     tokens, embh, hbuf0, hbuf1, flags);
    k_final<<<1, 64, 0, stream>>>(hbuf1, fc_w, fc_b, (float*)d_out);
}